// Round 1
// 4571.169 us; speedup vs baseline: 1.2137x; 1.2137x over previous
//
#include <hip/hip_runtime.h>
#include <math.h>

#define S_LEN 256
#define BATCH 64
#define NIN   1024
#define NH    2048
#define SCAN_BLOCKS  64    // 32 cols each
#define SCAN_THREADS 512   // 8 waves, K-split 8x256

typedef short s16x8 __attribute__((ext_vector_type(8)));
typedef float f32x4 __attribute__((ext_vector_type(4)));
typedef unsigned short u16x4 __attribute__((ext_vector_type(4)));

__device__ inline unsigned short f2bf(float f){
  unsigned int u = __float_as_uint(f);
  u += 0x7fffu + ((u >> 16) & 1u);      // round-to-nearest-even
  return (unsigned short)(u >> 16);
}

__global__ void k_cast_bf16(const float* __restrict__ in,
                            unsigned short* __restrict__ out, int n4){
  int i = blockIdx.x * blockDim.x + threadIdx.x;
  if (i >= n4) return;
  float4 v = ((const float4*)in)[i];
  u16x4 o;
  o.x = f2bf(v.x); o.y = f2bf(v.y); o.z = f2bf(v.z); o.w = f2bf(v.w);
  ((u16x4*)out)[i] = o;
}

// out[n][k] = bf16(in[k][n]);  K,N multiples of 32
__global__ void k_transpose_bf16(const float* __restrict__ in,
                                 unsigned short* __restrict__ out, int K, int N){
  __shared__ unsigned short tile[32][33];
  int n0 = blockIdx.x * 32, k0 = blockIdx.y * 32;
  int tx = threadIdx.x, ty = threadIdx.y;   // 32 x 8
  #pragma unroll
  for (int i = 0; i < 4; ++i)
    tile[ty + i*8][tx] = f2bf(in[(size_t)(k0 + ty + i*8) * N + n0 + tx]);
  __syncthreads();
  #pragma unroll
  for (int i = 0; i < 4; ++i)
    out[(size_t)(n0 + ty + i*8) * K + k0 + tx] = tile[tx][ty + i*8];
}

// base = x @ Wx + bx + bh  (fp32 into d_out)
__global__ __launch_bounds__(256) void k_xproj(
    const unsigned short* __restrict__ xbf,   // [16384][1024] bf16
    const unsigned short* __restrict__ wxt,   // [2048][1024]  bf16 (Wx^T)
    const float* __restrict__ bx,
    const float* __restrict__ bh,
    float* __restrict__ out)                  // [16384][2048] fp32
{
  int wave = threadIdx.x >> 6, lane = threadIdx.x & 63;
  int q = lane >> 4, r = lane & 15;
  int m0 = blockIdx.y * 64 + wave * 16;
  int n0 = blockIdx.x * 64;

  const unsigned short* arow = xbf + (size_t)(m0 + r) * NIN + q * 8;
  const unsigned short* brow = wxt + (size_t)(n0 + r) * NIN + q * 8;

  f32x4 acc[4] = {};
  #pragma unroll 2
  for (int kk = 0; kk < NIN; kk += 32){
    s16x8 a = *(const s16x8*)(arow + kk);
    #pragma unroll
    for (int j = 0; j < 4; ++j){
      s16x8 b = *(const s16x8*)(brow + (size_t)j * 16 * NIN + kk);
      acc[j] = __builtin_amdgcn_mfma_f32_16x16x32_bf16(a, b, acc[j], 0, 0, 0);
    }
  }
  #pragma unroll
  for (int j = 0; j < 4; ++j){
    int col = n0 + j * 16 + r;
    float bias = bx[col] + bh[col];
    #pragma unroll
    for (int i = 0; i < 4; ++i){
      int row = m0 + q * 4 + i;
      out[(size_t)row * NH + col] = acc[j][i] + bias;
    }
  }
}

// Persistent weight-stationary scan.
// 64 blocks x 512 thr (8 waves). Block owns 32 cols; waves K-split 8x256.
// Weight slice per wave: 16 frags = 64 VGPRs (register-resident).
// Barrier v2: padded per-block flag array (16B stride, monotone counter),
// wave-0 lane-parallel poll (one L3 round trip per poll, no atomics/sleep).
// All scan-cycle global stores device-scope (sc0 sc1) => L2 never dirty
// => acquire fence (buffer_inv) is cheap; flag release store needs no wb.
__global__ __launch_bounds__(SCAN_THREADS, 2) void k_scan_persist(
    unsigned short* __restrict__ hbuf,      // 2 x [64][2048] bf16 ping-pong (slot0 = h0)
    const unsigned short* __restrict__ wht, // [2048][2048] bf16 (Wh^T)
    float* __restrict__ out,                // [256][64][2048] fp32 (base in, tanh out)
    unsigned int* __restrict__ flags)       // 64 flags, stride 4 uints (16B), zeroed
{
  __shared__ float red[8][BATCH][36];       // +4 pad: write path 2-way (free)

  const int tid = threadIdx.x;
  const int wave = tid >> 6, lane = tid & 63;
  const int q = lane >> 4, r = lane & 15;
  const int n0 = blockIdx.x * 32;
  const int kbase = wave * 256;

  // ---- preload Wh^T slice into registers (once): 2 n-tiles x 8 k-tiles ----
  s16x8 breg[2][8];
  #pragma unroll
  for (int kk = 0; kk < 8; ++kk)
    #pragma unroll
    for (int j = 0; j < 2; ++j)
      breg[j][kk] = *(const s16x8*)(wht + (size_t)(n0 + j*16 + r) * NH + kbase + kk*32 + q*8);

  const int crow = tid >> 3;        // 0..63  (epilogue mapping)
  const int ccol = (tid & 7) * 4;   // 0..28
  const size_t g = (size_t)crow * NH + n0 + ccol;

  // prefetch base for t=0 (written by k_xproj; private to this thread)
  f32x4 base = *(const f32x4*)(out + g);

  for (int t = 0; t < S_LEN; ++t){
    const unsigned short* hc = hbuf + (size_t)(t & 1) * BATCH * NH;
    unsigned short* hn       = hbuf + (size_t)((t + 1) & 1) * BATCH * NH;
    float* outT = out + (size_t)t * BATCH * NH;

    // ---- wait: all blocks finished step t-1 ----
    if (t > 0){
      if (wave == 0){
        const unsigned int target = (unsigned int)t;
        const unsigned int* fp = flags + (lane << 2);   // 16B-strided flag per lane
        for (;;){
          unsigned int v = __hip_atomic_load(fp, __ATOMIC_RELAXED, __HIP_MEMORY_SCOPE_AGENT);
          if (__all((int)(v >= target))) break;
        }
        // make all blocks' device-scope h stores visible (inv L1/L2)
        __builtin_amdgcn_fence(__ATOMIC_ACQUIRE, "agent");
      }
      __syncthreads();              // (C) release waves 1..7; orders their h loads
    }

    // ---- partial GEMM over this wave's k-range (K=256) ----
    f32x4 acc[4][2] = {};
    #pragma unroll 4
    for (int kk = 0; kk < 8; ++kk){
      s16x8 a[4];
      #pragma unroll
      for (int m = 0; m < 4; ++m)
        a[m] = *(const s16x8*)(hc + (size_t)(m*16 + r) * NH + kbase + kk*32 + q*8);
      #pragma unroll
      for (int m = 0; m < 4; ++m)
        #pragma unroll
        for (int j = 0; j < 2; ++j)
          acc[m][j] = __builtin_amdgcn_mfma_f32_16x16x32_bf16(a[m], breg[j][kk], acc[m][j], 0, 0, 0);
    }

    // ---- single-pass K-reduce staging: all 8 waves write partials ----
    #pragma unroll
    for (int m = 0; m < 4; ++m)
      #pragma unroll
      for (int j = 0; j < 2; ++j)
        #pragma unroll
        for (int i = 0; i < 4; ++i)
          red[wave][m*16 + q*4 + i][j*16 + r] = acc[m][j][i];
    __syncthreads();                // (A)

    // ---- epilogue: all 512 threads, 4 elems each ----
    {
      f32x4 s = *(const f32x4*)&red[0][crow][ccol];
      #pragma unroll
      for (int w = 1; w < 8; ++w)
        s += *(const f32x4*)&red[w][crow][ccol];
      float tv[4];
      #pragma unroll
      for (int i = 0; i < 4; ++i) tv[i] = tanhf(base[i] + s[i]);

      union { float f[2]; unsigned long long u; } p0, p1;
      p0.f[0] = tv[0]; p0.f[1] = tv[1];
      p1.f[0] = tv[2]; p1.f[1] = tv[3];
      __hip_atomic_store((unsigned long long*)(outT + g),     p0.u,
                         __ATOMIC_RELAXED, __HIP_MEMORY_SCOPE_AGENT);
      __hip_atomic_store((unsigned long long*)(outT + g) + 1, p1.u,
                         __ATOMIC_RELAXED, __HIP_MEMORY_SCOPE_AGENT);
      union { unsigned short h[4]; unsigned long long u; } ph;
      #pragma unroll
      for (int i = 0; i < 4; ++i) ph.h[i] = f2bf(tv[i]);
      __hip_atomic_store((unsigned long long*)(hn + g), ph.u,
                         __ATOMIC_RELAXED, __HIP_MEMORY_SCOPE_AGENT);
    }

    __syncthreads();                // (B) drains each wave's vmcnt
                                    //     => sc0 sc1 stores at coherence pt
    if (tid == 0)
      __hip_atomic_store(flags + ((unsigned)blockIdx.x << 2), (unsigned int)(t + 1),
                         __ATOMIC_RELEASE, __HIP_MEMORY_SCOPE_AGENT);

    // prefetch next step's base: overlaps the poll (private to this thread)
    if (t + 1 < S_LEN)
      base = *(const f32x4*)(out + (size_t)(t + 1) * BATCH * NH + g);
  }
}

extern "C" void kernel_launch(void* const* d_in, const int* in_sizes, int n_in,
                              void* d_out, int out_size, void* d_ws, size_t ws_size,
                              hipStream_t stream){
  const float* x  = (const float*)d_in[0];
  const float* h0 = (const float*)d_in[1];
  const float* Wx = (const float*)d_in[2];
  const float* bx = (const float*)d_in[3];
  const float* Wh = (const float*)d_in[4];
  const float* bh = (const float*)d_in[5];
  float* out = (float*)d_out;

  char* ws = (char*)d_ws;
  unsigned short* xbf  = (unsigned short*)(ws);                               // 33,554,432 B
  unsigned short* wxt  = (unsigned short*)(ws + 33554432);                    //  4,194,304 B
  unsigned short* wht  = (unsigned short*)(ws + 33554432 + 4194304);          //  8,388,608 B
  unsigned short* hbuf = (unsigned short*)(ws + 33554432 + 4194304 + 8388608);//    524,288 B
  // flag array (64 x 16B) aliases xbf[0..512) — xbf is dead after k_xproj
  unsigned int* flags = (unsigned int*)ws;

  // 1) casts
  k_cast_bf16<<<dim3(16384), 256, 0, stream>>>(x,  xbf,  4194304);
  k_cast_bf16<<<dim3(128),   256, 0, stream>>>(h0, hbuf, 32768);
  // 2) weight transposes to [n][k] bf16
  k_transpose_bf16<<<dim3(NH/32, NIN/32), dim3(32, 8), 0, stream>>>(Wx, wxt, NIN, NH);
  k_transpose_bf16<<<dim3(NH/32, NH/32),  dim3(32, 8), 0, stream>>>(Wh, wht, NH, NH);
  // 3) base = x@Wx + bx + bh -> d_out
  k_xproj<<<dim3(NH/64, (S_LEN*BATCH)/64), 256, 0, stream>>>(xbf, wxt, bx, bh, out);
  // 4) zero flag array (xbf dead now), then persistent scan
  hipMemsetAsync(flags, 0, 1024, stream);
  {
    void* args[] = { (void*)&hbuf, (void*)&wht, (void*)&out, (void*)&flags };
    hipLaunchCooperativeKernel((const void*)k_scan_persist,
                               dim3(SCAN_BLOCKS), dim3(SCAN_THREADS), args, 0, stream);
  }
  // 5) hn = outputs[255]
  hipMemcpyAsync(out + (size_t)S_LEN * BATCH * NH,
                 out + (size_t)(S_LEN - 1) * BATCH * NH,
                 sizeof(float) * (size_t)BATCH * NH,
                 hipMemcpyDeviceToDevice, stream);
}